// Round 17
// baseline (310.142 us; speedup 1.0000x reference)
//
#include <hip/hip_runtime.h>
#include <hip/hip_bf16.h>

#define SLEN 512
#define BATCH 256
#define NIN 300
#define KP 320
#define NG 256
#define NH 64
#define BM 128
#define BN 128
#define BK 64
#define LDP 72   // padded LDS row length (f16) -> 144B rows, 2-way (free) b128 reads
#define TC 128   // steps per chunk
#define NCH (SLEN / TC)

typedef float f32x4 __attribute__((ext_vector_type(4)));
typedef _Float16 f16x8 __attribute__((ext_vector_type(8)));
typedef _Float16 f16x4 __attribute__((ext_vector_type(4)));
typedef unsigned short u16x4 __attribute__((ext_vector_type(4)));

// Build Wc16[n][k] (f16, K padded to 320), bcat[n], and Wg16[col][k] = f16(W_glt[k][col]).
__global__ void prep_w(const float* __restrict__ Wpt0, const float* __restrict__ bpt0,
                       const float* __restrict__ Wpt1, const float* __restrict__ bpt1,
                       const float* __restrict__ Wglt,
                       _Float16* __restrict__ Wc16, float* __restrict__ bcat,
                       _Float16* __restrict__ Wg16) {
  int idx = blockIdx.x * 256 + threadIdx.x;
  if (idx < NG * KP) {
    int n = idx / KP, k = idx - n * KP;
    int g = n >> 6, h = n & 63;
    float w = 0.f;
    if (k < NIN) {
      if (h < 32) w = Wpt0[k * 128 + g * 32 + h];
      else        w = 0.5f * Wpt1[(k >> 1) * 128 + g * 32 + (h - 32)];
    }
    Wc16[idx] = (_Float16)w;
  }
  if (idx < NG * NH) {  // transpose W_glt (64 x 256) -> Wg16 (256 x 64), f16
    int c = idx >> 6, k = idx & 63;
    Wg16[idx] = (_Float16)Wglt[k * NG + c];
  }
  if (idx < NG) {
    int g = idx >> 6, h = idx & 63;
    bcat[idx] = (h < 32) ? bpt0[g * 32 + h] : bpt1[g * 32 + h - 32];
  }
}

// ---------------- shared device bodies (used by standalone + fused) ----------

// C stored UNIT-MAJOR: C[row][unit*4 + gate]  (one 8B load per lane-step in rec)
__device__ __forceinline__ void gemm_body(
    char* LB, int m0, int n0, int tid,
    const float* __restrict__ x, const _Float16* __restrict__ Wc16,
    const float* __restrict__ bcat, _Float16* __restrict__ C) {
  _Float16 (*As)[LDP] = reinterpret_cast<_Float16(*)[LDP]>(LB);
  _Float16 (*Bs)[LDP] = reinterpret_cast<_Float16(*)[LDP]>(LB + BM * LDP * 2);
  const int lane = tid & 63;
  const int w = tid >> 6;
  const int wr = w >> 1, wc = w & 1;

  f32x4 acc[4][4];
#pragma unroll
  for (int m = 0; m < 4; ++m)
#pragma unroll
    for (int n = 0; n < 4; ++n) acc[m][n] = (f32x4){0.f, 0.f, 0.f, 0.f};

  const int arow_l = tid >> 4;        // 0..15
  const int acol   = (tid & 15) * 4;  // 0..60
  const int brow_l = tid >> 3;        // 0..31
  const int bcol   = (tid & 7) * 8;   // 0..56

  for (int k0 = 0; k0 < KP; k0 += BK) {
#pragma unroll
    for (int p = 0; p < 8; ++p) {
      int row = p * 16 + arow_l;
      int gk = k0 + acol;
      f32x4 v = (f32x4){0.f, 0.f, 0.f, 0.f};
      if (gk + 3 < NIN)  // 300 = 4*75: vectors never straddle the boundary
        v = *reinterpret_cast<const f32x4*>(&x[(size_t)(m0 + row) * NIN + gk]);
      f16x4 sv;
      sv[0] = (_Float16)v[0]; sv[1] = (_Float16)v[1];
      sv[2] = (_Float16)v[2]; sv[3] = (_Float16)v[3];
      *reinterpret_cast<f16x4*>(&As[row][acol]) = sv;
    }
#pragma unroll
    for (int p = 0; p < 4; ++p) {
      int n = p * 32 + brow_l;
      f16x8 v = *reinterpret_cast<const f16x8*>(&Wc16[(size_t)(n0 + n) * KP + k0 + bcol]);
      *reinterpret_cast<f16x8*>(&Bs[n][bcol]) = v;
    }
    __syncthreads();
#pragma unroll
    for (int ks = 0; ks < 2; ++ks) {
      const int kk = ks * 32 + (lane >> 4) * 8;
      f16x8 a[4], b[4];
#pragma unroll
      for (int m = 0; m < 4; ++m)
        a[m] = *reinterpret_cast<const f16x8*>(&As[wr * 64 + m * 16 + (lane & 15)][kk]);
#pragma unroll
      for (int n = 0; n < 4; ++n)
        b[n] = *reinterpret_cast<const f16x8*>(&Bs[wc * 64 + n * 16 + (lane & 15)][kk]);
#pragma unroll
      for (int m = 0; m < 4; ++m)
#pragma unroll
        for (int n = 0; n < 4; ++n)
          acc[m][n] = __builtin_amdgcn_mfma_f32_16x16x32_f16(a[m], b[n], acc[m][n], 0, 0, 0);
    }
    __syncthreads();
  }
  const int fc = lane & 15;
  const int fr = (lane >> 4) * 4;
#pragma unroll
  for (int n = 0; n < 4; ++n) {
    int col = n0 + wc * 64 + n * 16 + fc;
    int nidx = ((col & 63) << 2) | (col >> 6);   // unit-major store index
    float bias = bcat[col];
#pragma unroll
    for (int m = 0; m < 4; ++m) {
#pragma unroll
      for (int r = 0; r < 4; ++r) {
        int row = m0 + wr * 64 + m * 16 + fr + r;
        C[(size_t)row * NG + nidx] = (_Float16)(acc[m][n][r] + bias);
      }
    }
  }
}

__device__ __forceinline__ void decode_body(
    char* LB, int blk, int tid,
    const _Float16* __restrict__ hs, const float* __restrict__ Wdec,
    const float* __restrict__ bdec, float* __restrict__ out) {
  float* wl = reinterpret_cast<float*>(LB);          // 768 B
  float* bl = reinterpret_cast<float*>(LB + 768);    // 12 B
  float* ob = reinterpret_cast<float*>(LB + 784);    // 3072 B
  if (tid < NH * 3) wl[tid] = Wdec[tid];
  if (tid < 3) bl[tid] = bdec[tid];
  __syncthreads();
  const size_t idx = (size_t)blk * 256 + tid;
  const _Float16* hp = hs + idx * NH;
  float d0 = 0.f, d1 = 0.f, d2 = 0.f;
#pragma unroll
  for (int k = 0; k < NH; k += 8) {
    f16x8 h8 = *reinterpret_cast<const f16x8*>(&hp[k]);
#pragma unroll
    for (int j = 0; j < 8; ++j) {
      float hv = (float)h8[j];
      d0 += hv * wl[(k + j) * 3 + 0];
      d1 += hv * wl[(k + j) * 3 + 1];
      d2 += hv * wl[(k + j) * 3 + 2];
    }
  }
  ob[tid * 3 + 0] = d0 + bl[0];
  ob[tid * 3 + 1] = d1 + bl[1];
  ob[tid * 3 + 2] = d2 + bl[2];
  __syncthreads();
  if (tid < 192) {
    f32x4* o4 = reinterpret_cast<f32x4*>(out + (size_t)blk * 768);
    o4[tid] = reinterpret_cast<const f32x4*>(ob)[tid];
  }
}

// ---------------- rec-step macros: 1-wave, lane = unit, all 4 gates in-lane --
#define PAIR(v, j) __builtin_shufflevector(v, v, 2*(j), 2*(j)+1)
#define ACT1(SD, X, MUL, CL) { \
    float xx_ = fminf(fmaxf((X), -(CL)), (CL)); \
    float ee_ = __expf(-(MUL) * xx_); \
    SD = __builtin_amdgcn_rcpf(1.f + ee_); }

#define DOTCH(KK) { f16x8 hv = hb[KK]; \
    aF0 = __builtin_amdgcn_fdot2(PAIR(hv,0), PAIR(wF##KK,0), aF0, false); \
    aG0 = __builtin_amdgcn_fdot2(PAIR(hv,0), PAIR(wG##KK,0), aG0, false); \
    aI0 = __builtin_amdgcn_fdot2(PAIR(hv,0), PAIR(wI##KK,0), aI0, false); \
    aO0 = __builtin_amdgcn_fdot2(PAIR(hv,0), PAIR(wO##KK,0), aO0, false); \
    aF1 = __builtin_amdgcn_fdot2(PAIR(hv,1), PAIR(wF##KK,1), aF1, false); \
    aG1 = __builtin_amdgcn_fdot2(PAIR(hv,1), PAIR(wG##KK,1), aG1, false); \
    aI1 = __builtin_amdgcn_fdot2(PAIR(hv,1), PAIR(wI##KK,1), aI1, false); \
    aO1 = __builtin_amdgcn_fdot2(PAIR(hv,1), PAIR(wO##KK,1), aO1, false); \
    aF0 = __builtin_amdgcn_fdot2(PAIR(hv,2), PAIR(wF##KK,2), aF0, false); \
    aG0 = __builtin_amdgcn_fdot2(PAIR(hv,2), PAIR(wG##KK,2), aG0, false); \
    aI0 = __builtin_amdgcn_fdot2(PAIR(hv,2), PAIR(wI##KK,2), aI0, false); \
    aO0 = __builtin_amdgcn_fdot2(PAIR(hv,2), PAIR(wO##KK,2), aO0, false); \
    aF1 = __builtin_amdgcn_fdot2(PAIR(hv,3), PAIR(wF##KK,3), aF1, false); \
    aG1 = __builtin_amdgcn_fdot2(PAIR(hv,3), PAIR(wG##KK,3), aG1, false); \
    aI1 = __builtin_amdgcn_fdot2(PAIR(hv,3), PAIR(wI##KK,3), aI1, false); \
    aO1 = __builtin_amdgcn_fdot2(PAIR(hv,3), PAIR(wO##KK,3), aO1, false); }

#define STEP(CURV) { \
    float pF = (float)__builtin_bit_cast(_Float16, (unsigned short)(CURV)[0]); \
    float pG = (float)__builtin_bit_cast(_Float16, (unsigned short)(CURV)[1]); \
    float pI = (float)__builtin_bit_cast(_Float16, (unsigned short)(CURV)[2]); \
    float pO = (float)__builtin_bit_cast(_Float16, (unsigned short)(CURV)[3]); \
    const f16x8* hb = reinterpret_cast<const f16x8*>(hbuf); \
    float aF0 = 0.f, aF1 = 0.f, aG0 = 0.f, aG1 = 0.f; \
    float aI0 = 0.f, aI1 = 0.f, aO0 = 0.f, aO1 = 0.f; \
    DOTCH(0) DOTCH(1) DOTCH(2) DOTCH(3) DOTCH(4) DOTCH(5) DOTCH(6) DOTCH(7) \
    pF += aF0 + aF1; pG += aG0 + aG1; pI += aI0 + aI1; pO += aO0 + aO1; \
    float sF, sG2, sI, sO; \
    ACT1(sF, pF, 1.f, 30.f) ACT1(sG2, pG, 2.f, 15.f) \
    ACT1(sI, pI, 1.f, 30.f) ACT1(sO, pO, 1.f, 30.f) \
    float tG = 2.f * sG2 - 1.f; \
    float c1 = sF * creg + sI * tG; creg = c1; \
    float sT2; ACT1(sT2, c1, 2.f, 15.f) \
    float th = 2.f * sT2 - 1.f; \
    float h1 = sO * th; hreg = h1; \
    hbuf[l] = (_Float16)h1;              /* in-wave in-order LDS: safe single buffer */ \
    *hp = (_Float16)h1; hp += (size_t)BATCH * NH;  /* fire-and-forget */ \
    asm volatile("s_waitcnt lgkmcnt(0)" ::: "memory"); }

// ---------------- standalone kernels (chunk 0 gemm, final decode) ------------

__global__ __launch_bounds__(256, 2) void gemm_i2h(
    const float* __restrict__ x, const _Float16* __restrict__ Wc16,
    const float* __restrict__ bcat, _Float16* __restrict__ C) {
  __shared__ __align__(16) char LB[36864];
  gemm_body(LB, blockIdx.y * BM, blockIdx.x * BN, threadIdx.x, x, Wc16, bcat, C);
}

__global__ __launch_bounds__(256) void decode(
    const _Float16* __restrict__ hs, const float* __restrict__ Wdec,
    const float* __restrict__ bdec, float* __restrict__ out) {
  __shared__ __align__(16) char LB[4096];
  decode_body(LB, blockIdx.x, threadIdx.x, hs, Wdec, bdec, out);
}

// ---------------- fused chunk kernel ----------------------------------------
// bid < 256            : rec for chunk k — ONE WAVE does the loop (waves 1-3
//                        stage weights then exit; no barrier in the step loop)
// next 512 (gemm)      : i2h GEMM for chunk k+1 (rides on the 3 idle SIMDs)
// rest (dec)           : decode of chunk k-1
__global__ __launch_bounds__(256, 2)
void fused_step(
    const _Float16* __restrict__ i2h_cur, _Float16* __restrict__ i2h_next,
    const float* __restrict__ x_next,
    const _Float16* __restrict__ Wc16, const float* __restrict__ bcat,
    const _Float16* __restrict__ Wg16,
    const float* __restrict__ h_in, const float* __restrict__ c_in,
    float* __restrict__ h_state, float* __restrict__ c_state,
    _Float16* __restrict__ hs_cur, const _Float16* __restrict__ hs_prev,
    const float* __restrict__ Wdec, const float* __restrict__ bdec,
    float* __restrict__ out_prev,
    float* __restrict__ hT_out, float* __restrict__ cT_out,
    int is_last, int has_gemm) {
  __shared__ __align__(16) char LB[36864];
  const int bid = blockIdx.x;
  const int tid = threadIdx.x;

  if (bid < BATCH) {
    // ------------------ rec role: 1-wave, lane = unit -----------------------
    const int b = bid;
    const int l = tid & 63;

    f16x8* Wst = reinterpret_cast<f16x8*>(LB);            // Wst[kk*256 + col]
    unsigned hoff = 0;
    asm volatile("" : "+s"(hoff));                        // opaque 0
    _Float16* hbuf = reinterpret_cast<_Float16*>(LB + hoff);

    // stage weights (all 4 waves), conflict-free [kk][col] layout
    for (int e = tid; e < 8 * NG; e += 256) {
      int kk = e >> 8, c = e & 255;
      Wst[e] = *reinterpret_cast<const f16x8*>(Wg16 + (size_t)c * NH + kk * 8);
    }
    __syncthreads();
    if (tid >= 64) return;   // waves 1-3 done; no barriers remain below

    // weights -> 32 named f16x8 (128 VGPRs). Reads are from LB; the hbuf
    // write below is through an OPAQUE base -> may-alias -> remat illegal.
#define LW(G, N, KK) f16x8 w##N##KK = Wst[(KK) * NG + (G) * 64 + l];
#define LWROW(G, N) LW(G,N,0) LW(G,N,1) LW(G,N,2) LW(G,N,3) LW(G,N,4) LW(G,N,5) LW(G,N,6) LW(G,N,7)
    LWROW(0, F) LWROW(1, G) LWROW(2, I) LWROW(3, O)

    float creg = c_in[b * NH + l];
    float hreg = h_in[b * NH + l];
    hbuf[l] = (_Float16)hreg;            // overwrite -> pins weights in VGPRs
    asm volatile("s_waitcnt lgkmcnt(0)" ::: "memory");

    const size_t S4 = (size_t)NG * BATCH / 4;   // u16x4 elems per step
    const u16x4* ip = reinterpret_cast<const u16x4*>(
        reinterpret_cast<const unsigned short*>(i2h_cur) + (size_t)b * NG) + l;
    _Float16* hp = hs_cur + (size_t)b * NH + l;

    int s = 0;
    {
      u16x4 c0v = ip[0],      c1v = ip[S4],     c2v = ip[2 * S4], c3v = ip[3 * S4];
      u16x4 n0v = ip[4 * S4], n1v = ip[5 * S4], n2v = ip[6 * S4], n3v = ip[7 * S4];
      const u16x4* ipf = ip + 8 * S4;
      while (s + 4 <= TC) {
        u16x4 f0v = (u16x4){0, 0, 0, 0}, f1v = f0v, f2v = f0v, f3v = f0v;
        if (s + 8  < TC) f0v = ipf[0];        // uniform guard; nothing reads
        if (s + 9  < TC) f1v = ipf[S4];       // the reg until STEP next quad
        if (s + 10 < TC) f2v = ipf[2 * S4];
        if (s + 11 < TC) f3v = ipf[3 * S4];
        ipf += 4 * S4;
        STEP(c0v)
        STEP(c1v)
        STEP(c2v)
        STEP(c3v)
        c0v = n0v; c1v = n1v; c2v = n2v; c3v = n3v;   // waits: loads 1 quad old
        n0v = f0v; n1v = f1v; n2v = f2v; n3v = f3v;   // waits: loads this quad top
        s += 4;
      }
    }

    h_state[b * NH + l] = hreg;
    c_state[b * NH + l] = creg;
    if (is_last) {
      hT_out[b * NH + l] = hreg;
      cT_out[b * NH + l] = creg;
    }
  } else if (has_gemm && bid < BATCH + 2 * (TC * BATCH / BM)) {
    // ------------------ gemm role: i2h for chunk k+1 ------------------------
    const int gid = bid - BATCH;
    const int n0 = (gid & 1) * BN;      // N-pair adjacent -> x slab L2 reuse
    const int m0 = (gid >> 1) * BM;
    gemm_body(LB, m0, n0, tid, x_next, Wc16, bcat, i2h_next);
  } else {
    // ------------------ decode role: chunk k-1 ------------------------------
    const int did = bid - BATCH - (has_gemm ? 2 * (TC * BATCH / BM) : 0);
    decode_body(LB, did, tid, hs_prev, Wdec, bdec, out_prev);
  }
}

extern "C" void kernel_launch(void* const* d_in, const int* in_sizes, int n_in,
                              void* d_out, int out_size, void* d_ws, size_t ws_size,
                              hipStream_t stream) {
  const float* x    = (const float*)d_in[0];
  const float* h0   = (const float*)d_in[1];
  const float* c0   = (const float*)d_in[2];
  const float* Wpt0 = (const float*)d_in[3];
  const float* bpt0 = (const float*)d_in[4];
  const float* Wpt1 = (const float*)d_in[5];
  const float* bpt1 = (const float*)d_in[6];
  const float* Wglt = (const float*)d_in[7];
  const float* Wdec = (const float*)d_in[8];
  const float* bdec = (const float*)d_in[9];
  float* out = (float*)d_out;

  char* ws = (char*)d_ws;
  _Float16*  Wc16    = (_Float16*)(ws);           // 163840 B
  float*     bcat    = (float*)(ws + 163840);     // 1 KB
  _Float16*  Wg16    = (_Float16*)(ws + 164864);  // 32768 B (256 x 64 f16)
  float*     h_state = (float*)(ws + 197632);     // 64 KB
  float*     c_state = (float*)(ws + 263168);     // 64 KB
  const size_t base = 328704;

  const size_t chunk_i2h = (size_t)TC * BATCH * NG;     // f16 elems per chunk
  _Float16* i2h0 = (_Float16*)(ws + base);
  _Float16* i2h1 = i2h0 + chunk_i2h;
  _Float16* hs   = (_Float16*)(ws + base + 4 * chunk_i2h);  // 2 bufs * 2 B

  prep_w<<<dim3((NG * KP + 255) / 256), dim3(256), 0, stream>>>(
      Wpt0, bpt0, Wpt1, bpt1, Wglt, Wc16, bcat, Wg16);

  // chunk 0 GEMM (full GPU, nothing to overlap with yet)
  gemm_i2h<<<dim3(2, TC * BATCH / BM), dim3(256), 0, stream>>>(
      x, Wc16, bcat, i2h0);

  for (int k = 0; k < NCH; ++k) {
    _Float16* cur = (k & 1) ? i2h1 : i2h0;
    _Float16* nxt = (k & 1) ? i2h0 : i2h1;
    const int has_gemm = (k + 1 < NCH) ? 1 : 0;
    const int has_dec  = (k > 0) ? 1 : 0;
    const int nblk = BATCH + (has_gemm ? 2 * (TC * BATCH / BM) : 0)
                           + (has_dec ? (TC * BATCH / 256) : 0);
    const int kp = (k > 0) ? (k - 1) : 0;
    fused_step<<<dim3(nblk), dim3(256), 0, stream>>>(
        cur, nxt, x + (size_t)(k + 1) * TC * BATCH * NIN,
        Wc16, bcat, Wg16,
        (k == 0) ? h0 : h_state, (k == 0) ? c0 : c_state,
        h_state, c_state,
        hs + (size_t)k * TC * BATCH * NH,
        hs + (size_t)kp * TC * BATCH * NH,
        Wdec, bdec,
        out + (size_t)kp * TC * BATCH * 3,
        out + (size_t)SLEN * BATCH * 3,
        out + (size_t)SLEN * BATCH * 3 + BATCH * NH,
        (k == NCH - 1) ? 1 : 0, has_gemm);
  }

  // decode of the last chunk
  decode<<<dim3(TC * BATCH / 256), dim3(256), 0, stream>>>(
      hs + (size_t)(NCH - 1) * TC * BATCH * NH, Wdec, bdec,
      out + (size_t)(NCH - 1) * TC * BATCH * 3);
}

// Round 18
// 247.284 us; speedup vs baseline: 1.2542x; 1.2542x over previous
//
#include <hip/hip_runtime.h>
#include <hip/hip_bf16.h>

#define SLEN 512
#define BATCH 256
#define NIN 300
#define KP 320
#define NG 256
#define NH 64
#define BM 128
#define BN 128
#define BK 64
#define LDP 72   // padded LDS row length (f16) -> 144B rows, 2-way (free) b128 reads
#define TC 128   // steps per chunk
#define NCH (SLEN / TC)

typedef float f32x4 __attribute__((ext_vector_type(4)));
typedef _Float16 f16x8 __attribute__((ext_vector_type(8)));
typedef _Float16 f16x4 __attribute__((ext_vector_type(4)));

// quad-lane broadcast via DPP quad_perm [J,J,J,J] — VALU-speed cross-lane
template <int J>
__device__ __forceinline__ float quad_bcast(float v) {
  return __builtin_bit_cast(float,
      __builtin_amdgcn_mov_dpp(__builtin_bit_cast(int, v),
                               J * 0x55, 0xf, 0xf, true));
}

// Build Wc16[n][k] (f16, K padded to 320), bcat[n], and Wg16[col][k] = f16(W_glt[k][col]).
__global__ void prep_w(const float* __restrict__ Wpt0, const float* __restrict__ bpt0,
                       const float* __restrict__ Wpt1, const float* __restrict__ bpt1,
                       const float* __restrict__ Wglt,
                       _Float16* __restrict__ Wc16, float* __restrict__ bcat,
                       _Float16* __restrict__ Wg16) {
  int idx = blockIdx.x * 256 + threadIdx.x;
  if (idx < NG * KP) {
    int n = idx / KP, k = idx - n * KP;
    int g = n >> 6, h = n & 63;
    float w = 0.f;
    if (k < NIN) {
      if (h < 32) w = Wpt0[k * 128 + g * 32 + h];
      else        w = 0.5f * Wpt1[(k >> 1) * 128 + g * 32 + (h - 32)];
    }
    Wc16[idx] = (_Float16)w;
  }
  if (idx < NG * NH) {  // transpose W_glt (64 x 256) -> Wg16 (256 x 64), f16
    int c = idx >> 6, k = idx & 63;
    Wg16[idx] = (_Float16)Wglt[k * NG + c];
  }
  if (idx < NG) {
    int g = idx >> 6, h = idx & 63;
    bcat[idx] = (h < 32) ? bpt0[g * 32 + h] : bpt1[g * 32 + h - 32];
  }
}

// ---------------- shared device bodies (used by standalone + fused) ----------

__device__ __forceinline__ void gemm_body(
    char* LB, int m0, int n0, int tid,
    const float* __restrict__ x, const _Float16* __restrict__ Wc16,
    const float* __restrict__ bcat, _Float16* __restrict__ C) {
  _Float16 (*As)[LDP] = reinterpret_cast<_Float16(*)[LDP]>(LB);
  _Float16 (*Bs)[LDP] = reinterpret_cast<_Float16(*)[LDP]>(LB + BM * LDP * 2);
  const int lane = tid & 63;
  const int w = tid >> 6;
  const int wr = w >> 1, wc = w & 1;

  f32x4 acc[4][4];
#pragma unroll
  for (int m = 0; m < 4; ++m)
#pragma unroll
    for (int n = 0; n < 4; ++n) acc[m][n] = (f32x4){0.f, 0.f, 0.f, 0.f};

  const int arow_l = tid >> 4;        // 0..15
  const int acol   = (tid & 15) * 4;  // 0..60
  const int brow_l = tid >> 3;        // 0..31
  const int bcol   = (tid & 7) * 8;   // 0..56

  for (int k0 = 0; k0 < KP; k0 += BK) {
#pragma unroll
    for (int p = 0; p < 8; ++p) {
      int row = p * 16 + arow_l;
      int gk = k0 + acol;
      f32x4 v = (f32x4){0.f, 0.f, 0.f, 0.f};
      if (gk + 3 < NIN)  // 300 = 4*75: vectors never straddle the boundary
        v = *reinterpret_cast<const f32x4*>(&x[(size_t)(m0 + row) * NIN + gk]);
      f16x4 sv;
      sv[0] = (_Float16)v[0]; sv[1] = (_Float16)v[1];
      sv[2] = (_Float16)v[2]; sv[3] = (_Float16)v[3];
      *reinterpret_cast<f16x4*>(&As[row][acol]) = sv;
    }
#pragma unroll
    for (int p = 0; p < 4; ++p) {
      int n = p * 32 + brow_l;
      f16x8 v = *reinterpret_cast<const f16x8*>(&Wc16[(size_t)(n0 + n) * KP + k0 + bcol]);
      *reinterpret_cast<f16x8*>(&Bs[n][bcol]) = v;
    }
    __syncthreads();
#pragma unroll
    for (int ks = 0; ks < 2; ++ks) {
      const int kk = ks * 32 + (lane >> 4) * 8;
      f16x8 a[4], b[4];
#pragma unroll
      for (int m = 0; m < 4; ++m)
        a[m] = *reinterpret_cast<const f16x8*>(&As[wr * 64 + m * 16 + (lane & 15)][kk]);
#pragma unroll
      for (int n = 0; n < 4; ++n)
        b[n] = *reinterpret_cast<const f16x8*>(&Bs[wc * 64 + n * 16 + (lane & 15)][kk]);
#pragma unroll
      for (int m = 0; m < 4; ++m)
#pragma unroll
        for (int n = 0; n < 4; ++n)
          acc[m][n] = __builtin_amdgcn_mfma_f32_16x16x32_f16(a[m], b[n], acc[m][n], 0, 0, 0);
    }
    __syncthreads();
  }
  const int fc = lane & 15;
  const int fr = (lane >> 4) * 4;
#pragma unroll
  for (int n = 0; n < 4; ++n) {
    int col = n0 + wc * 64 + n * 16 + fc;
    float bias = bcat[col];
#pragma unroll
    for (int m = 0; m < 4; ++m) {
#pragma unroll
      for (int r = 0; r < 4; ++r) {
        int row = m0 + wr * 64 + m * 16 + fr + r;
        C[(size_t)row * NG + col] = (_Float16)(acc[m][n][r] + bias);
      }
    }
  }
}

__device__ __forceinline__ void decode_body(
    char* LB, int blk, int tid,
    const _Float16* __restrict__ hs, const float* __restrict__ Wdec,
    const float* __restrict__ bdec, float* __restrict__ out) {
  float* wl = reinterpret_cast<float*>(LB);          // 768 B
  float* bl = reinterpret_cast<float*>(LB + 768);    // 12 B
  float* ob = reinterpret_cast<float*>(LB + 784);    // 3072 B
  if (tid < NH * 3) wl[tid] = Wdec[tid];
  if (tid < 3) bl[tid] = bdec[tid];
  __syncthreads();
  const size_t idx = (size_t)blk * 256 + tid;
  const _Float16* hp = hs + idx * NH;
  float d0 = 0.f, d1 = 0.f, d2 = 0.f;
#pragma unroll
  for (int k = 0; k < NH; k += 8) {
    f16x8 h8 = *reinterpret_cast<const f16x8*>(&hp[k]);
#pragma unroll
    for (int j = 0; j < 8; ++j) {
      float hv = (float)h8[j];
      d0 += hv * wl[(k + j) * 3 + 0];
      d1 += hv * wl[(k + j) * 3 + 1];
      d2 += hv * wl[(k + j) * 3 + 2];
    }
  }
  ob[tid * 3 + 0] = d0 + bl[0];
  ob[tid * 3 + 1] = d1 + bl[1];
  ob[tid * 3 + 2] = d2 + bl[2];
  __syncthreads();
  if (tid < 192) {
    f32x4* o4 = reinterpret_cast<f32x4*>(out + (size_t)blk * 768);
    o4[tid] = reinterpret_cast<const f32x4*>(ob)[tid];
  }
}

// rec-step macros: quad-layout (lane = unit*4 + gate), DPP gate exchange
#define PAIR(v, j) __builtin_shufflevector(v, v, 2*(j), 2*(j)+1)
#define DOT(hb, i, W) { f16x8 hv = (hb)[i]; \
      acc0 = __builtin_amdgcn_fdot2(PAIR(hv,0), PAIR(W,0), acc0, false); \
      acc1 = __builtin_amdgcn_fdot2(PAIR(hv,1), PAIR(W,1), acc1, false); \
      acc0 = __builtin_amdgcn_fdot2(PAIR(hv,2), PAIR(W,2), acc0, false); \
      acc1 = __builtin_amdgcn_fdot2(PAIR(hv,3), PAIR(W,3), acc1, false); }

#define STEP(CUR, SP) { \
    float cur_ = (float)__builtin_bit_cast(_Float16, (unsigned short)(CUR)); \
    const f16x8* hb = reinterpret_cast<const f16x8*>(hbuf + ((SP) & 1) * NH); \
    float acc0 = 0.f, acc1 = 0.f; \
    DOT(hb, 0, w0) DOT(hb, 1, w1) DOT(hb, 2, w2) DOT(hb, 3, w3) \
    DOT(hb, 4, w4) DOT(hb, 5, w5) DOT(hb, 6, w6) DOT(hb, 7, w7) \
    float pre = cur_ + (acc0 + acc1); \
    float xx = fminf(fmaxf(pre, -30.f), 30.f); \
    float e = __expf(-mm * xx); \
    float y = 1.f / (1.f + e); \
    float act = (qid == 1) ? (2.f * y - 1.f) : y; \
    float f_ = quad_bcast<0>(act); \
    float g_ = quad_bcast<1>(act); \
    float i_ = quad_bcast<2>(act); \
    float o_ = quad_bcast<3>(act); \
    float c1 = f_ * creg + i_ * g_;   /* all 4 quad lanes, redundant */ \
    creg = c1; \
    float ct = fminf(fmaxf(c1, -15.f), 15.f); \
    float e2 = __expf(-2.f * ct); \
    float th = (1.f - e2) / (1.f + e2); \
    float h1 = o_ * th; \
    hreg = h1; \
    if (qid == 0) { \
      hbuf[(((SP) + 1) & 1) * NH + unit] = (_Float16)h1; \
      *hp = (_Float16)h1;  /* fire-and-forget */ \
    } \
    hp += st >> 2; /* BATCH*NH f16 per step */ \
    asm volatile("s_waitcnt lgkmcnt(0)" ::: "memory"); \
    __builtin_amdgcn_s_barrier(); }

// ---------------- standalone kernels (chunk 0 gemm, final decode) ------------

__global__ __launch_bounds__(256, 2) void gemm_i2h(
    const float* __restrict__ x, const _Float16* __restrict__ Wc16,
    const float* __restrict__ bcat, _Float16* __restrict__ C) {
  __shared__ __align__(16) char LB[36864];
  gemm_body(LB, blockIdx.y * BM, blockIdx.x * BN, threadIdx.x, x, Wc16, bcat, C);
}

__global__ __launch_bounds__(256) void decode(
    const _Float16* __restrict__ hs, const float* __restrict__ Wdec,
    const float* __restrict__ bdec, float* __restrict__ out) {
  __shared__ __align__(16) char LB[4096];
  decode_body(LB, blockIdx.x, threadIdx.x, hs, Wdec, bdec, out);
}

// ---------------- fused chunk kernel ----------------------------------------
// bid < 256            : rec for chunk k (quad-layout, 1 block/row, 4 waves)
//                        runs at s_setprio(1): the rec wave is the serial
//                        critical path; co-resident gemm waves are dense
//                        issuers that otherwise steal ~half the issue slots.
// bid < 256+512 (gemm) : i2h GEMM for chunk k+1 (prio 0, absorbs rec stalls)
// rest (dec)           : decode of chunk k-1
__global__ __launch_bounds__(256, 2)
void fused_step(
    const _Float16* __restrict__ i2h_cur, _Float16* __restrict__ i2h_next,
    const float* __restrict__ x_next,
    const _Float16* __restrict__ Wc16, const float* __restrict__ bcat,
    const _Float16* __restrict__ Wg16,
    const float* __restrict__ h_in, const float* __restrict__ c_in,
    float* __restrict__ h_state, float* __restrict__ c_state,
    _Float16* __restrict__ hs_cur, const _Float16* __restrict__ hs_prev,
    const float* __restrict__ Wdec, const float* __restrict__ bdec,
    float* __restrict__ out_prev,
    float* __restrict__ hT_out, float* __restrict__ cT_out,
    int is_last, int has_gemm) {
  __shared__ __align__(16) char LB[36864];
  const int bid = blockIdx.x;
  const int tid = threadIdx.x;

  if (bid < BATCH) {
    // ------------------ rec role (quad layout, T = TC) ----------------------
    const int b = bid;
    const int ww = tid >> 6;
    const int l = tid & 63;
    const int qid = l & 3;              // gate index within quad
    const int unit = ww * 16 + (l >> 2);
    const int col = qid * 64 + unit;    // gate column in [0,256)

    f16x8* Wst = reinterpret_cast<f16x8*>(LB);           // Wst[kk*256 + c]
    _Float16* hbuf = reinterpret_cast<_Float16*>(LB);    // hbuf[(s&1)*64 + u]

    for (int e = tid; e < 8 * NG; e += 256) {
      int kk = e >> 8, c = e & 255;
      Wst[e] = *reinterpret_cast<const f16x8*>(Wg16 + (size_t)c * NH + kk * 8);
    }
    __syncthreads();

    f16x8 w0 = Wst[0 * NG + col], w1 = Wst[1 * NG + col];
    f16x8 w2 = Wst[2 * NG + col], w3 = Wst[3 * NG + col];
    f16x8 w4 = Wst[4 * NG + col], w5 = Wst[5 * NG + col];
    f16x8 w6 = Wst[6 * NG + col], w7 = Wst[7 * NG + col];

    float creg = c_in[b * NH + unit];   // replicated per quad, deterministic
    float hreg = 0.f;
    float h0v = (tid < NH) ? h_in[b * NH + tid] : 0.f;
    __syncthreads();   // all weight reads done before the overwrite below

    if (tid < NH) hbuf[tid] = (_Float16)h0v;   // clobbers weight region
    __syncthreads();

    __builtin_amdgcn_s_setprio(1);      // rec = critical chain: win issue arb

    const size_t st = (size_t)NG * BATCH;      // i2h f16 elems per step
    const unsigned short* ip =
        reinterpret_cast<const unsigned short*>(i2h_cur) + (size_t)b * NG + col;
    _Float16* hp = hs_cur + (size_t)b * NH + unit;
    const float mm = (qid == 1) ? 2.f : 1.f;

    int s = 0;
    {
      unsigned short c0v = ip[0],      c1v = ip[st],     c2v = ip[2 * st], c3v = ip[3 * st];
      unsigned short n0v = ip[4 * st], n1v = ip[5 * st], n2v = ip[6 * st], n3v = ip[7 * st];
      const unsigned short* ipf = ip + 8 * st;
      while (s + 4 <= TC) {
        unsigned short f0v = 0, f1v = 0, f2v = 0, f3v = 0;
        if (s + 8  < TC) f0v = ipf[0];        // uniform branch; nothing reads
        if (s + 9  < TC) f1v = ipf[st];       // the reg until STEP next quad
        if (s + 10 < TC) f2v = ipf[2 * st];
        if (s + 11 < TC) f3v = ipf[3 * st];
        ipf += 4 * st;
        STEP(c0v, s)
        STEP(c1v, s + 1)
        STEP(c2v, s + 2)
        STEP(c3v, s + 3)
        c0v = n0v; c1v = n1v; c2v = n2v; c3v = n3v;   // waits: loads 1 quad old
        n0v = f0v; n1v = f1v; n2v = f2v; n3v = f3v;   // waits: loads this quad top
        s += 4;
      }
    }
    __builtin_amdgcn_s_setprio(0);

    if (qid == 0) {
      h_state[b * NH + unit] = hreg;
      c_state[b * NH + unit] = creg;
      if (is_last) {
        hT_out[b * NH + unit] = hreg;
        cT_out[b * NH + unit] = creg;
      }
    }
  } else if (has_gemm && bid < BATCH + 2 * (TC * BATCH / BM)) {
    // ------------------ gemm role: i2h for chunk k+1 ------------------------
    const int gid = bid - BATCH;
    const int n0 = (gid & 1) * BN;      // N-pair adjacent -> x slab L2 reuse
    const int m0 = (gid >> 1) * BM;
    gemm_body(LB, m0, n0, tid, x_next, Wc16, bcat, i2h_next);
  } else {
    // ------------------ decode role: chunk k-1 ------------------------------
    const int did = bid - BATCH - (has_gemm ? 2 * (TC * BATCH / BM) : 0);
    decode_body(LB, did, tid, hs_prev, Wdec, bdec, out_prev);
  }
}

extern "C" void kernel_launch(void* const* d_in, const int* in_sizes, int n_in,
                              void* d_out, int out_size, void* d_ws, size_t ws_size,
                              hipStream_t stream) {
  const float* x    = (const float*)d_in[0];
  const float* h0   = (const float*)d_in[1];
  const float* c0   = (const float*)d_in[2];
  const float* Wpt0 = (const float*)d_in[3];
  const float* bpt0 = (const float*)d_in[4];
  const float* Wpt1 = (const float*)d_in[5];
  const float* bpt1 = (const float*)d_in[6];
  const float* Wglt = (const float*)d_in[7];
  const float* Wdec = (const float*)d_in[8];
  const float* bdec = (const float*)d_in[9];
  float* out = (float*)d_out;

  char* ws = (char*)d_ws;
  _Float16*  Wc16    = (_Float16*)(ws);           // 163840 B
  float*     bcat    = (float*)(ws + 163840);     // 1 KB
  _Float16*  Wg16    = (_Float16*)(ws + 164864);  // 32768 B (256 x 64 f16)
  float*     h_state = (float*)(ws + 197632);     // 64 KB
  float*     c_state = (float*)(ws + 263168);     // 64 KB
  const size_t base = 328704;

  const size_t chunk_i2h = (size_t)TC * BATCH * NG;     // f16 elems per chunk
  _Float16* i2h0 = (_Float16*)(ws + base);
  _Float16* i2h1 = i2h0 + chunk_i2h;
  _Float16* hs   = (_Float16*)(ws + base + 4 * chunk_i2h);  // 2 bufs * 2 B

  prep_w<<<dim3((NG * KP + 255) / 256), dim3(256), 0, stream>>>(
      Wpt0, bpt0, Wpt1, bpt1, Wglt, Wc16, bcat, Wg16);

  // chunk 0 GEMM (full GPU, nothing to overlap with yet)
  gemm_i2h<<<dim3(2, TC * BATCH / BM), dim3(256), 0, stream>>>(
      x, Wc16, bcat, i2h0);

  for (int k = 0; k < NCH; ++k) {
    _Float16* cur = (k & 1) ? i2h1 : i2h0;
    _Float16* nxt = (k & 1) ? i2h0 : i2h1;
    const int has_gemm = (k + 1 < NCH) ? 1 : 0;
    const int has_dec  = (k > 0) ? 1 : 0;
    const int nblk = BATCH + (has_gemm ? 2 * (TC * BATCH / BM) : 0)
                           + (has_dec ? (TC * BATCH / 256) : 0);
    const int kp = (k > 0) ? (k - 1) : 0;
    fused_step<<<dim3(nblk), dim3(256), 0, stream>>>(
        cur, nxt, x + (size_t)(k + 1) * TC * BATCH * NIN,
        Wc16, bcat, Wg16,
        (k == 0) ? h0 : h_state, (k == 0) ? c0 : c_state,
        h_state, c_state,
        hs + (size_t)k * TC * BATCH * NH,
        hs + (size_t)kp * TC * BATCH * NH,
        Wdec, bdec,
        out + (size_t)kp * TC * BATCH * 3,
        out + (size_t)SLEN * BATCH * 3,
        out + (size_t)SLEN * BATCH * 3 + BATCH * NH,
        (k == NCH - 1) ? 1 : 0, has_gemm);
  }

  // decode of the last chunk
  decode<<<dim3(TC * BATCH / 256), dim3(256), 0, stream>>>(
      hs + (size_t)(NCH - 1) * TC * BATCH * NH, Wdec, bdec,
      out + (size_t)(NCH - 1) * TC * BATCH * 3);
}